// Round 1
// baseline (8490.781 us; speedup 1.0000x reference)
//
#include <hip/hip_runtime.h>
#include <stdint.h>

// LSTM: B=64, S=512, I=1024, H=1024.  fp32 in/out, bf16 MFMA internally.
// Phase 1: Xg = bf16(X) @ bf16(Wx) + b   (32768x4096x1024 GEMM, 128x128 tiles)
// Phase 2: persistent 256-block scan kernel; 4 groups x 64 WGs;
//          Wh register-resident; group barrier per step.

typedef unsigned short ushort_t;
typedef unsigned int uint_t;
typedef __attribute__((ext_vector_type(8))) short bf16x8;
typedef __attribute__((ext_vector_type(4))) float f32x4;

typedef __attribute__((address_space(1))) void gvoid;
typedef __attribute__((address_space(3))) void lvoid;

// ---- workspace layout (bytes) ----
static const unsigned long long OFF_XBF  = 0ull;                       // 32768*1024*2 = 64MB
static const unsigned long long OFF_WXT  = 67108864ull;                // 4096*1024*2  =  8MB
static const unsigned long long OFF_WHT  = 75497472ull;                // 4096*1024*2  =  8MB
static const unsigned long long OFF_BIAS = 83886080ull;                // 4096*4 = 16KB
static const unsigned long long OFF_HBUF = 83902464ull;                // 4 groups * 2 parity * 32KB = 256KB
static const unsigned long long OFF_BAR  = 84164608ull;                // 4KB barrier counters
static const unsigned long long OFF_XG   = 84168704ull;                // Xg: 512MB f32 or 256MB bf16
static const unsigned long long NEED_F32 = OFF_XG + 536870912ull;
// out layout: result[64][512][1024] f32, then H_f[64][1024], then C_f[64][1024]
static const unsigned long long HF_OFF = 33554432ull;
static const unsigned long long CF_OFF = 33619968ull;

__device__ __forceinline__ ushort_t f2bf(float f) {
    uint_t u = __float_as_uint(f);
    return (ushort_t)((u + 0x7FFFu + ((u >> 16) & 1u)) >> 16);
}
__device__ __forceinline__ float bf2f(ushort_t u) {
    return __uint_as_float(((uint_t)u) << 16);
}
__device__ __forceinline__ float sigm(float x) { return 1.f / (1.f + __expf(-x)); }
__device__ __forceinline__ float tanh_(float x) { return 2.f / (1.f + __expf(-2.f * x)) - 1.f; }

// ---------------- X fp32 -> bf16 ----------------
__global__ void cvt_x_kernel(const float* __restrict__ X, ushort_t* __restrict__ Xb) {
    size_t i = ((size_t)blockIdx.x * 256u + threadIdx.x) * 8u;
    const float4* p = (const float4*)(X + i);
    float4 a = p[0], c = p[1];
    bf16x8 v;
    v[0] = (short)f2bf(a.x); v[1] = (short)f2bf(a.y);
    v[2] = (short)f2bf(a.z); v[3] = (short)f2bf(a.w);
    v[4] = (short)f2bf(c.x); v[5] = (short)f2bf(c.y);
    v[6] = (short)f2bf(c.z); v[7] = (short)f2bf(c.w);
    *(bf16x8*)(Xb + i) = v;
}

// ---------------- pack weights ----------------
// WxT[n][k] = W_x{g=n>>10}[k][n&1023]          (B^T layout for phase-1 GEMM)
// WhT[r][k] = W_h{g=r&3}[k][r>>2]              (gate-interleaved rows: r = 4*h + g)
// bias[g*1024+h] = b_g[h]
__global__ void pack_w_kernel(
    const float* Wxi, const float* Whi, const float* bi,
    const float* Wxf, const float* Whf, const float* bfv,
    const float* Wxo, const float* Who, const float* bo,
    const float* Wxc, const float* Whc, const float* bc,
    ushort_t* __restrict__ WxT, ushort_t* __restrict__ WhT, float* __restrict__ bias) {
    uint_t id = blockIdx.x * 256u + threadIdx.x;
    const float* WX[4] = {Wxi, Wxf, Wxo, Wxc};
    const float* WH[4] = {Whi, Whf, Who, Whc};
    const float* BB[4] = {bi, bfv, bo, bc};
    if (id < 524288u) {
        uint_t n = id >> 7, sg = id & 127u;
        uint_t gate = n >> 10, hh = n & 1023u;
        const float* src = WX[gate] + hh;
        uint_t k0 = sg * 8u;
        bf16x8 v;
#pragma unroll
        for (int j = 0; j < 8; ++j) v[j] = (short)f2bf(src[(size_t)(k0 + j) * 1024u]);
        *(bf16x8*)(WxT + (size_t)n * 1024u + k0) = v;
    } else if (id < 1048576u) {
        uint_t id2 = id - 524288u;
        uint_t rr = id2 >> 7, sg = id2 & 127u;
        uint_t hh = rr >> 2, gate = rr & 3u;
        const float* src = WH[gate] + hh;
        uint_t k0 = sg * 8u;
        bf16x8 v;
#pragma unroll
        for (int j = 0; j < 8; ++j) v[j] = (short)f2bf(src[(size_t)(k0 + j) * 1024u]);
        *(bf16x8*)(WhT + (size_t)rr * 1024u + k0) = v;
    } else if (id < 1052672u) {
        uint_t id3 = id - 1048576u;
        bias[id3] = BB[id3 >> 10][id3 & 1023u];
    }
}

// ---------------- phase 1 GEMM: Xg = Xbf @ WxT^T + bias ----------------
// 128x128 tile, BK=64, 4 waves, global_load_lds staging, XOR-swizzled LDS.
__global__ __launch_bounds__(256) void gemm_xg_kernel(
    const ushort_t* __restrict__ Xb, const ushort_t* __restrict__ WxT,
    const float* __restrict__ bias, char* __restrict__ Xg, int xg32) {
    __shared__ ushort_t Atile[128 * 64];
    __shared__ ushort_t Btile[128 * 64];
    uint_t bid = blockIdx.x;
    uint_t swz = (bid & 7u) * 1024u + (bid >> 3);   // XCD-contiguous chunks
    uint_t bm = swz >> 5, bn = swz & 31u;
    uint_t tid = threadIdx.x, lane = tid & 63u, wv = tid >> 6;
    uint_t vm = wv >> 1, vn = wv & 1u;
    f32x4 acc[4][4];
#pragma unroll
    for (int m = 0; m < 4; ++m)
#pragma unroll
        for (int n = 0; n < 4; ++n) acc[m][n] = (f32x4){0.f, 0.f, 0.f, 0.f};

    const ushort_t* Abase = Xb + (size_t)bm * 128u * 1024u;
    const ushort_t* Bbase = WxT + (size_t)bn * 128u * 1024u;

    for (int ks = 0; ks < 16; ++ks) {
#pragma unroll
        for (int r = 0; r < 4; ++r) {
            uint_t i2 = (r * 4u + wv) * 64u + lane;
            uint_t row = i2 >> 3;
            uint_t kb = (i2 & 7u) * 16u;
            uint_t skb = kb ^ ((row & 7u) << 4);       // inverse-swizzled SOURCE
            const char* asrc = (const char*)(Abase + (size_t)row * 1024u + ks * 64) + skb;
            const char* bsrc = (const char*)(Bbase + (size_t)row * 1024u + ks * 64) + skb;
            char* adst = (char*)Atile + (r * 4u + wv) * 1024u;  // wave-uniform, linear dest
            char* bdst = (char*)Btile + (r * 4u + wv) * 1024u;
            __builtin_amdgcn_global_load_lds((const gvoid*)asrc, (lvoid*)adst, 16, 0, 0);
            __builtin_amdgcn_global_load_lds((const gvoid*)bsrc, (lvoid*)bdst, 16, 0, 0);
        }
        asm volatile("s_waitcnt vmcnt(0)" ::: "memory");
        __syncthreads();
#pragma unroll
        for (int kt = 0; kt < 2; ++kt) {
            bf16x8 af[4], bfr[4];
#pragma unroll
            for (int mt = 0; mt < 4; ++mt) {
                uint_t row = vm * 64u + mt * 16u + (lane & 15u);
                uint_t kb = (uint_t)(kt * 64 + (int)((lane >> 4) * 16u)) ^ ((row & 7u) << 4);
                af[mt] = *(const bf16x8*)((const char*)Atile + row * 128u + kb);
            }
#pragma unroll
            for (int nt = 0; nt < 4; ++nt) {
                uint_t row = vn * 64u + nt * 16u + (lane & 15u);
                uint_t kb = (uint_t)(kt * 64 + (int)((lane >> 4) * 16u)) ^ ((row & 7u) << 4);
                bfr[nt] = *(const bf16x8*)((const char*)Btile + row * 128u + kb);
            }
#pragma unroll
            for (int mt = 0; mt < 4; ++mt)
#pragma unroll
                for (int nt = 0; nt < 4; ++nt)
                    acc[mt][nt] = __builtin_amdgcn_mfma_f32_16x16x32_bf16(af[mt], bfr[nt], acc[mt][nt], 0, 0, 0);
        }
        __syncthreads();
    }
    float bv[4];
#pragma unroll
    for (int nt = 0; nt < 4; ++nt) bv[nt] = bias[bn * 128u + vn * 64u + nt * 16u + (lane & 15u)];
#pragma unroll
    for (int mt = 0; mt < 4; ++mt)
#pragma unroll
        for (int r = 0; r < 4; ++r) {
            size_t grow = (size_t)bm * 128u + vm * 64u + mt * 16u + (lane >> 4) * 4u + r;
#pragma unroll
            for (int nt = 0; nt < 4; ++nt) {
                uint_t col = bn * 128u + vn * 64u + nt * 16u + (lane & 15u);
                float v = acc[mt][nt][r] + bv[nt];
                if (xg32) ((float*)Xg)[grow * 4096u + col] = v;
                else ((ushort_t*)Xg)[grow * 4096u + col] = f2bf(v);
            }
        }
}

// ---------------- phase 2: persistent scan ----------------
// 256 WGs x 256 thr. group g = wg>>6 owns seqs [16g,16g+16); WG w = wg&63 owns h in [16w,16w+16).
// Wh rows r = 4h+g; wave wv owns K-slice kt in [8wv, 8wv+8); cross-wave K-reduce via LDS.
// Each thread (seq=tid>>4, hl=tid&15) owns one (h,b) cell; C stays in a register.
__global__ __launch_bounds__(256, 1) void lstm_scan_kernel(
    const ushort_t* __restrict__ WhT, const char* __restrict__ Xg,
    float* __restrict__ out, ushort_t* __restrict__ Hbuf, uint_t* __restrict__ bar, int xg32) {
    __shared__ float part[4][64][17];
    uint_t wg = blockIdx.x;
    uint_t g = wg >> 6, w = wg & 63u;
    uint_t tid = threadIdx.x, lane = tid & 63u, wv = tid >> 6;

    // register-resident Wh fragments (statically indexed)
    bf16x8 wh[4][8];
#pragma unroll
    for (int mt = 0; mt < 4; ++mt)
#pragma unroll
        for (int q = 0; q < 8; ++q) {
            uint_t row = w * 64u + mt * 16u + (lane & 15u);
            uint_t kk = (wv * 8u + q) * 32u + (lane >> 4) * 8u;
            wh[mt][q] = *(const bf16x8*)(WhT + (size_t)row * 1024u + kk);
        }

    uint_t seq = tid >> 4, hl = tid & 15u;
    uint_t b = g * 16u + seq;
    uint_t h = w * 16u + hl;
    float C = 0.f;

    ushort_t* HbA = Hbuf + (size_t)g * 32768u;  // parity 0
    ushort_t* HbB = HbA + 16384u;               // parity 1 (zeroed; read at t=0)
    uint_t k5 = (w & 1u) * 16u + hl;
    uint_t kt_w = w >> 1;
    uint_t hoff = kt_w * 512u + (seq + ((k5 >> 3) << 4)) * 8u + (k5 & 7u);
    uint_t* cnt = bar + g * 64u;

    float xgc[4], xgn[4];
    {
        size_t xrow = ((size_t)b * 512u) * 4096u + h;
#pragma unroll
        for (int gg = 0; gg < 4; ++gg)
            xgc[gg] = xg32 ? ((const float*)Xg)[xrow + gg * 1024u]
                           : bf2f(((const ushort_t*)Xg)[xrow + gg * 1024u]);
    }

    for (int t = 0; t < 512; ++t) {
        const ushort_t* Hsrc = (t & 1) ? HbA : HbB;
        ushort_t* Hdst = (t & 1) ? HbB : HbA;
        f32x4 acc[4];
#pragma unroll
        for (int mt = 0; mt < 4; ++mt) acc[mt] = (f32x4){0.f, 0.f, 0.f, 0.f};
#pragma unroll
        for (int q = 0; q < 8; ++q) {
            bf16x8 hf = *(const bf16x8*)(Hsrc + (wv * 8u + q) * 512u + lane * 8u);
#pragma unroll
            for (int mt = 0; mt < 4; ++mt)
                acc[mt] = __builtin_amdgcn_mfma_f32_16x16x32_bf16(wh[mt][q], hf, acc[mt], 0, 0, 0);
        }
#pragma unroll
        for (int mt = 0; mt < 4; ++mt)
#pragma unroll
            for (int r = 0; r < 4; ++r)
                part[wv][mt * 16u + (lane >> 4) * 4u + r][lane & 15u] = acc[mt][r];
        if (t < 511) {  // prefetch next step's xg (independent of barrier)
            size_t xrow = ((size_t)b * 512u + (uint_t)(t + 1)) * 4096u + h;
#pragma unroll
            for (int gg = 0; gg < 4; ++gg)
                xgn[gg] = xg32 ? ((const float*)Xg)[xrow + gg * 1024u]
                               : bf2f(((const ushort_t*)Xg)[xrow + gg * 1024u]);
        }
        __syncthreads();
        float pre[4];
#pragma unroll
        for (int gg = 0; gg < 4; ++gg) {
            uint_t l = 4u * hl + gg;
            pre[gg] = part[0][l][seq] + part[1][l][seq] + part[2][l][seq] + part[3][l][seq] + xgc[gg];
        }
        float i_ = sigm(pre[0]);
        float f_ = sigm(pre[1]);
        float o_ = sigm(pre[2]);
        float cc = tanh_(pre[3]);
        C = f_ * C + i_ * cc;
        float ho = o_ * tanh_(C);
        out[((size_t)b * 512u + (uint_t)t) * 1024u + h] = ho;
        Hdst[hoff] = f2bf(ho);
        if (t == 511) {
            out[HF_OFF + (size_t)b * 1024u + h] = ho;
            out[CF_OFF + (size_t)b * 1024u + h] = C;
        }
#pragma unroll
        for (int gg = 0; gg < 4; ++gg) xgc[gg] = xgn[gg];
        __syncthreads();
        if (tid == 0) {
            uint_t target = 64u * (uint_t)(t + 1);
            uint_t v = __hip_atomic_fetch_add(cnt, 1u, __ATOMIC_ACQ_REL, __HIP_MEMORY_SCOPE_AGENT) + 1u;
            int guard = 0;
            while (v < target && guard < (1 << 22)) {
                __builtin_amdgcn_s_sleep(2);
                v = __hip_atomic_load(cnt, __ATOMIC_ACQUIRE, __HIP_MEMORY_SCOPE_AGENT);
                ++guard;
            }
        }
        __syncthreads();
    }
}

extern "C" void kernel_launch(void* const* d_in, const int* in_sizes, int n_in,
                              void* d_out, int out_size, void* d_ws, size_t ws_size,
                              hipStream_t stream) {
    const float* X   = (const float*)d_in[0];
    const float* Wxi = (const float*)d_in[1];
    const float* Whi = (const float*)d_in[2];
    const float* bi  = (const float*)d_in[3];
    const float* Wxf = (const float*)d_in[4];
    const float* Whf = (const float*)d_in[5];
    const float* bfv = (const float*)d_in[6];
    const float* Wxo = (const float*)d_in[7];
    const float* Who = (const float*)d_in[8];
    const float* bo  = (const float*)d_in[9];
    const float* Wxc = (const float*)d_in[10];
    const float* Whc = (const float*)d_in[11];
    const float* bc  = (const float*)d_in[12];
    char* ws = (char*)d_ws;
    float* out = (float*)d_out;
    int xg32 = (ws_size >= NEED_F32) ? 1 : 0;

    hipMemsetAsync(ws + OFF_HBUF, 0, (size_t)(OFF_XG - OFF_HBUF), stream);

    cvt_x_kernel<<<16384, 256, 0, stream>>>(X, (ushort_t*)(ws + OFF_XBF));
    pack_w_kernel<<<4112, 256, 0, stream>>>(Wxi, Whi, bi, Wxf, Whf, bfv, Wxo, Who, bo, Wxc, Whc, bc,
                                            (ushort_t*)(ws + OFF_WXT), (ushort_t*)(ws + OFF_WHT),
                                            (float*)(ws + OFF_BIAS));
    gemm_xg_kernel<<<8192, 256, 0, stream>>>((const ushort_t*)(ws + OFF_XBF),
                                             (const ushort_t*)(ws + OFF_WXT),
                                             (const float*)(ws + OFF_BIAS), ws + OFF_XG, xg32);
    lstm_scan_kernel<<<256, 256, 0, stream>>>((const ushort_t*)(ws + OFF_WHT), ws + OFF_XG,
                                              out, (ushort_t*)(ws + OFF_HBUF),
                                              (uint_t*)(ws + OFF_BAR), xg32);
}

// Round 2
// 4349.286 us; speedup vs baseline: 1.9522x; 1.9522x over previous
//
#include <hip/hip_runtime.h>
#include <stdint.h>

// LSTM: B=64, S=512, I=1024, H=1024.  fp32 in/out, bf16 MFMA internally.
// Phase 1: Xg = bf16(X) @ bf16(Wx) + b   (32768x4096x1024 GEMM, 128x128 tiles)
// Phase 2: persistent 256-block scan kernel; 4 groups x 64 WGs x 8 waves;
//          Wh register-resident; flag-array barrier (no RMW, no L2 flush).

typedef unsigned short ushort_t;
typedef unsigned int uint_t;
typedef unsigned long long u64_t;
typedef __attribute__((ext_vector_type(8))) short bf16x8;
typedef __attribute__((ext_vector_type(4))) float f32x4;

typedef __attribute__((address_space(1))) void gvoid;
typedef __attribute__((address_space(3))) void lvoid;

// ---- workspace layout (bytes) ----
static const unsigned long long OFF_XBF  = 0ull;                       // 32768*1024*2 = 64MB
static const unsigned long long OFF_WXT  = 67108864ull;                // 4096*1024*2  =  8MB
static const unsigned long long OFF_WHT  = 75497472ull;                // 4096*1024*2  =  8MB
static const unsigned long long OFF_BIAS = 83886080ull;                // 4096*4 = 16KB
static const unsigned long long OFF_HBUF = 83902464ull;                // 4 groups * 2 parity * 32KB = 256KB
static const unsigned long long OFF_BAR  = 84164608ull;                // 4KB flag array
static const unsigned long long OFF_XG   = 84168704ull;                // Xg: 512MB f32 or 256MB bf16
static const unsigned long long NEED_F32 = OFF_XG + 536870912ull;
// out layout: result[64][512][1024] f32, then H_f[64][1024], then C_f[64][1024]
static const unsigned long long HF_OFF = 33554432ull;
static const unsigned long long CF_OFF = 33619968ull;

__device__ __forceinline__ ushort_t f2bf(float f) {
    uint_t u = __float_as_uint(f);
    return (ushort_t)((u + 0x7FFFu + ((u >> 16) & 1u)) >> 16);
}
__device__ __forceinline__ float bf2f(ushort_t u) {
    return __uint_as_float(((uint_t)u) << 16);
}
__device__ __forceinline__ float sigm(float x) { return 1.f / (1.f + __expf(-x)); }
__device__ __forceinline__ float tanh_(float x) { return 2.f / (1.f + __expf(-2.f * x)) - 1.f; }

// ---------------- X fp32 -> bf16 ----------------
__global__ void cvt_x_kernel(const float* __restrict__ X, ushort_t* __restrict__ Xb) {
    size_t i = ((size_t)blockIdx.x * 256u + threadIdx.x) * 8u;
    const float4* p = (const float4*)(X + i);
    float4 a = p[0], c = p[1];
    bf16x8 v;
    v[0] = (short)f2bf(a.x); v[1] = (short)f2bf(a.y);
    v[2] = (short)f2bf(a.z); v[3] = (short)f2bf(a.w);
    v[4] = (short)f2bf(c.x); v[5] = (short)f2bf(c.y);
    v[6] = (short)f2bf(c.z); v[7] = (short)f2bf(c.w);
    *(bf16x8*)(Xb + i) = v;
}

// ---------------- pack weights ----------------
// WxT[n][k] = W_x{g=n>>10}[k][n&1023]          (B^T layout for phase-1 GEMM)
// WhT[r][k] = W_h{g=r&3}[k][r>>2]              (gate-interleaved rows: r = 4*h + g)
// bias[g*1024+h] = b_g[h]
__global__ void pack_w_kernel(
    const float* Wxi, const float* Whi, const float* bi,
    const float* Wxf, const float* Whf, const float* bfv,
    const float* Wxo, const float* Who, const float* bo,
    const float* Wxc, const float* Whc, const float* bc,
    ushort_t* __restrict__ WxT, ushort_t* __restrict__ WhT, float* __restrict__ bias) {
    uint_t id = blockIdx.x * 256u + threadIdx.x;
    const float* WX[4] = {Wxi, Wxf, Wxo, Wxc};
    const float* WH[4] = {Whi, Whf, Who, Whc};
    const float* BB[4] = {bi, bfv, bo, bc};
    if (id < 524288u) {
        uint_t n = id >> 7, sg = id & 127u;
        uint_t gate = n >> 10, hh = n & 1023u;
        const float* src = WX[gate] + hh;
        uint_t k0 = sg * 8u;
        bf16x8 v;
#pragma unroll
        for (int j = 0; j < 8; ++j) v[j] = (short)f2bf(src[(size_t)(k0 + j) * 1024u]);
        *(bf16x8*)(WxT + (size_t)n * 1024u + k0) = v;
    } else if (id < 1048576u) {
        uint_t id2 = id - 524288u;
        uint_t rr = id2 >> 7, sg = id2 & 127u;
        uint_t hh = rr >> 2, gate = rr & 3u;
        const float* src = WH[gate] + hh;
        uint_t k0 = sg * 8u;
        bf16x8 v;
#pragma unroll
        for (int j = 0; j < 8; ++j) v[j] = (short)f2bf(src[(size_t)(k0 + j) * 1024u]);
        *(bf16x8*)(WhT + (size_t)rr * 1024u + k0) = v;
    } else if (id < 1052672u) {
        uint_t id3 = id - 1048576u;
        bias[id3] = BB[id3 >> 10][id3 & 1023u];
    }
}

// ---------------- phase 1 GEMM: Xg = Xbf @ WxT^T + bias ----------------
// 128x128 tile, BK=64, 4 waves, global_load_lds staging, XOR-swizzled LDS.
__global__ __launch_bounds__(256) void gemm_xg_kernel(
    const ushort_t* __restrict__ Xb, const ushort_t* __restrict__ WxT,
    const float* __restrict__ bias, char* __restrict__ Xg, int xg32) {
    __shared__ ushort_t Atile[128 * 64];
    __shared__ ushort_t Btile[128 * 64];
    uint_t bid = blockIdx.x;
    uint_t swz = (bid & 7u) * 1024u + (bid >> 3);   // XCD-contiguous chunks
    uint_t bm = swz >> 5, bn = swz & 31u;
    uint_t tid = threadIdx.x, lane = tid & 63u, wv = tid >> 6;
    uint_t vm = wv >> 1, vn = wv & 1u;
    f32x4 acc[4][4];
#pragma unroll
    for (int m = 0; m < 4; ++m)
#pragma unroll
        for (int n = 0; n < 4; ++n) acc[m][n] = (f32x4){0.f, 0.f, 0.f, 0.f};

    const ushort_t* Abase = Xb + (size_t)bm * 128u * 1024u;
    const ushort_t* Bbase = WxT + (size_t)bn * 128u * 1024u;

    for (int ks = 0; ks < 16; ++ks) {
#pragma unroll
        for (int r = 0; r < 4; ++r) {
            uint_t i2 = (r * 4u + wv) * 64u + lane;
            uint_t row = i2 >> 3;
            uint_t kb = (i2 & 7u) * 16u;
            uint_t skb = kb ^ ((row & 7u) << 4);       // inverse-swizzled SOURCE
            const char* asrc = (const char*)(Abase + (size_t)row * 1024u + ks * 64) + skb;
            const char* bsrc = (const char*)(Bbase + (size_t)row * 1024u + ks * 64) + skb;
            char* adst = (char*)Atile + (r * 4u + wv) * 1024u;  // wave-uniform, linear dest
            char* bdst = (char*)Btile + (r * 4u + wv) * 1024u;
            __builtin_amdgcn_global_load_lds((const gvoid*)asrc, (lvoid*)adst, 16, 0, 0);
            __builtin_amdgcn_global_load_lds((const gvoid*)bsrc, (lvoid*)bdst, 16, 0, 0);
        }
        asm volatile("s_waitcnt vmcnt(0)" ::: "memory");
        __syncthreads();
#pragma unroll
        for (int kt = 0; kt < 2; ++kt) {
            bf16x8 af[4], bfr[4];
#pragma unroll
            for (int mt = 0; mt < 4; ++mt) {
                uint_t row = vm * 64u + mt * 16u + (lane & 15u);
                uint_t kb = (uint_t)(kt * 64 + (int)((lane >> 4) * 16u)) ^ ((row & 7u) << 4);
                af[mt] = *(const bf16x8*)((const char*)Atile + row * 128u + kb);
            }
#pragma unroll
            for (int nt = 0; nt < 4; ++nt) {
                uint_t row = vn * 64u + nt * 16u + (lane & 15u);
                uint_t kb = (uint_t)(kt * 64 + (int)((lane >> 4) * 16u)) ^ ((row & 7u) << 4);
                bfr[nt] = *(const bf16x8*)((const char*)Btile + row * 128u + kb);
            }
#pragma unroll
            for (int mt = 0; mt < 4; ++mt)
#pragma unroll
                for (int nt = 0; nt < 4; ++nt)
                    acc[mt][nt] = __builtin_amdgcn_mfma_f32_16x16x32_bf16(af[mt], bfr[nt], acc[mt][nt], 0, 0, 0);
        }
        __syncthreads();
    }
    float bv[4];
#pragma unroll
    for (int nt = 0; nt < 4; ++nt) bv[nt] = bias[bn * 128u + vn * 64u + nt * 16u + (lane & 15u)];
#pragma unroll
    for (int mt = 0; mt < 4; ++mt)
#pragma unroll
        for (int r = 0; r < 4; ++r) {
            size_t grow = (size_t)bm * 128u + vm * 64u + mt * 16u + (lane >> 4) * 4u + r;
#pragma unroll
            for (int nt = 0; nt < 4; ++nt) {
                uint_t col = bn * 128u + vn * 64u + nt * 16u + (lane & 15u);
                float v = acc[mt][nt][r] + bv[nt];
                if (xg32) ((float*)Xg)[grow * 4096u + col] = v;
                else ((ushort_t*)Xg)[grow * 4096u + col] = f2bf(v);
            }
        }
}

// ---------------- phase 2: persistent scan ----------------
// 256 WGs x 512 thr (8 waves). group g = wg>>6 owns seqs [16g,16g+16);
// WG w = wg&63 owns h in [16w,16w+16) (Wh rows r=4h+g, 64 rows, reg-resident).
// Wave wv in [0,8) owns K-slice [128*wv, 128*wv+128); cross-wave reduce via LDS.
// Cross-WG H + flags move via relaxed AGENT atomics (sc1, L3-coherent, no L2
// maintenance). Barrier = one flag store per WG + wave0 parallel poll of 64 flags.
__global__ __launch_bounds__(512, 1) void lstm_scan_kernel(
    const ushort_t* __restrict__ WhT, const char* __restrict__ Xg,
    float* __restrict__ out, ushort_t* __restrict__ Hbuf, uint_t* __restrict__ bar, int xg32) {
    __shared__ float part[8][64][17];
    uint_t wg = blockIdx.x;
    uint_t g = wg >> 6, w = wg & 63u;
    uint_t tid = threadIdx.x, lane = tid & 63u, wv = tid >> 6;

    // register-resident Wh fragments: 16 x bf16x8 = 64 VGPRs/lane
    bf16x8 wh[4][4];
#pragma unroll
    for (int mt = 0; mt < 4; ++mt)
#pragma unroll
        for (int q = 0; q < 4; ++q) {
            uint_t row = w * 64u + mt * 16u + (lane & 15u);
            uint_t kk = (wv * 4u + q) * 32u + (lane >> 4) * 8u;
            wh[mt][q] = *(const bf16x8*)(WhT + (size_t)row * 1024u + kk);
        }

    bool comp = tid < 256u;          // computing cell threads
    uint_t seq = tid >> 4, hl = tid & 15u;   // valid when comp
    uint_t b = g * 16u + seq;
    uint_t h = w * 16u + hl;
    float C = 0.f;

    ushort_t* HbA = Hbuf + (size_t)g * 32768u;  // parity 0
    ushort_t* HbB = HbA + 16384u;               // parity 1 (zeroed; read at t=0)
    uint_t k5 = (w & 1u) * 16u + hl;
    uint_t kt_w = w >> 1;
    uint_t hoff = kt_w * 512u + (seq + ((k5 >> 3) << 4)) * 8u + (k5 & 7u);
    uint_t* flags = bar + g * 64u;   // 64 dwords per group (256B, group-aligned)

    float xgc[4], xgn[4];
    if (comp) {
        size_t xrow = ((size_t)b * 512u) * 4096u + h;
#pragma unroll
        for (int gg = 0; gg < 4; ++gg)
            xgc[gg] = xg32 ? ((const float*)Xg)[xrow + gg * 1024u]
                           : bf2f(((const ushort_t*)Xg)[xrow + gg * 1024u]);
    }

    for (int t = 0; t < 512; ++t) {
        const ushort_t* Hsrc = (t & 1) ? HbA : HbB;
        ushort_t* Hdst = (t & 1) ? HbB : HbA;
        f32x4 acc[4];
#pragma unroll
        for (int mt = 0; mt < 4; ++mt) acc[mt] = (f32x4){0.f, 0.f, 0.f, 0.f};
#pragma unroll
        for (int q = 0; q < 4; ++q) {
            u64_t* hp = (u64_t*)(Hsrc + ((wv * 4u + q) * 512u + lane * 8u));
            u64_t lo = __hip_atomic_load(hp, __ATOMIC_RELAXED, __HIP_MEMORY_SCOPE_AGENT);
            u64_t hi = __hip_atomic_load(hp + 1, __ATOMIC_RELAXED, __HIP_MEMORY_SCOPE_AGENT);
            union { u64_t q2[2]; bf16x8 v; } uu;
            uu.q2[0] = lo; uu.q2[1] = hi;
#pragma unroll
            for (int mt = 0; mt < 4; ++mt)
                acc[mt] = __builtin_amdgcn_mfma_f32_16x16x32_bf16(wh[mt][q], uu.v, acc[mt], 0, 0, 0);
        }
#pragma unroll
        for (int mt = 0; mt < 4; ++mt)
#pragma unroll
            for (int r = 0; r < 4; ++r)
                part[wv][mt * 16u + (lane >> 4) * 4u + r][lane & 15u] = acc[mt][r];
        if (comp && t < 511) {  // prefetch next step's xg (plain cached loads)
            size_t xrow = ((size_t)b * 512u + (uint_t)(t + 1)) * 4096u + h;
#pragma unroll
            for (int gg = 0; gg < 4; ++gg)
                xgn[gg] = xg32 ? ((const float*)Xg)[xrow + gg * 1024u]
                               : bf2f(((const ushort_t*)Xg)[xrow + gg * 1024u]);
        }
        __syncthreads();
        if (comp) {
            float pre[4];
#pragma unroll
            for (int gg = 0; gg < 4; ++gg) {
                uint_t l = 4u * hl + gg;
                float s = part[0][l][seq] + part[1][l][seq] + part[2][l][seq] + part[3][l][seq]
                        + part[4][l][seq] + part[5][l][seq] + part[6][l][seq] + part[7][l][seq];
                pre[gg] = s + xgc[gg];
            }
            float i_ = sigm(pre[0]);
            float f_ = sigm(pre[1]);
            float o_ = sigm(pre[2]);
            float cc = tanh_(pre[3]);
            C = f_ * C + i_ * cc;
            float ho = o_ * tanh_(C);
            __builtin_nontemporal_store(ho, &out[((size_t)b * 512u + (uint_t)t) * 1024u + h]);
            // pack 2 bf16 (lane pair) -> one 32-bit agent-scope store (sc1, L3-visible)
            uint_t hb = (uint_t)f2bf(ho);
            uint_t other = __shfl_xor(hb, 1);
            if ((lane & 1u) == 0u) {
                uint_t packed = hb | (other << 16);
                __hip_atomic_store((uint_t*)Hdst + (hoff >> 1), packed,
                                   __ATOMIC_RELAXED, __HIP_MEMORY_SCOPE_AGENT);
            }
            if (t == 511) {
                __builtin_nontemporal_store(ho, &out[HF_OFF + (size_t)b * 1024u + h]);
                __builtin_nontemporal_store(C, &out[CF_OFF + (size_t)b * 1024u + h]);
            }
#pragma unroll
            for (int gg = 0; gg < 4; ++gg) xgc[gg] = xgn[gg];
        }
        __syncthreads();   // drains all H stores (vmcnt 0) before flag publish
        if (t < 511) {
            uint_t target = (uint_t)(t + 1);
            if (tid == 0)
                __hip_atomic_store(&flags[w], target, __ATOMIC_RELAXED, __HIP_MEMORY_SCOPE_AGENT);
            if (wv == 0) {
                uint_t v;
                int guard = 0;
                do {
                    v = __hip_atomic_load(&flags[lane], __ATOMIC_RELAXED, __HIP_MEMORY_SCOPE_AGENT);
                } while (__any(v < target) && ++guard < (1 << 20));
            }
            __syncthreads();
        }
    }
}

extern "C" void kernel_launch(void* const* d_in, const int* in_sizes, int n_in,
                              void* d_out, int out_size, void* d_ws, size_t ws_size,
                              hipStream_t stream) {
    const float* X   = (const float*)d_in[0];
    const float* Wxi = (const float*)d_in[1];
    const float* Whi = (const float*)d_in[2];
    const float* bi  = (const float*)d_in[3];
    const float* Wxf = (const float*)d_in[4];
    const float* Whf = (const float*)d_in[5];
    const float* bfv = (const float*)d_in[6];
    const float* Wxo = (const float*)d_in[7];
    const float* Who = (const float*)d_in[8];
    const float* bo  = (const float*)d_in[9];
    const float* Wxc = (const float*)d_in[10];
    const float* Whc = (const float*)d_in[11];
    const float* bc  = (const float*)d_in[12];
    char* ws = (char*)d_ws;
    float* out = (float*)d_out;
    int xg32 = (ws_size >= NEED_F32) ? 1 : 0;

    hipMemsetAsync(ws + OFF_HBUF, 0, (size_t)(OFF_XG - OFF_HBUF), stream);

    cvt_x_kernel<<<16384, 256, 0, stream>>>(X, (ushort_t*)(ws + OFF_XBF));
    pack_w_kernel<<<4112, 256, 0, stream>>>(Wxi, Whi, bi, Wxf, Whf, bfv, Wxo, Who, bo, Wxc, Whc, bc,
                                            (ushort_t*)(ws + OFF_WXT), (ushort_t*)(ws + OFF_WHT),
                                            (float*)(ws + OFF_BIAS));
    gemm_xg_kernel<<<8192, 256, 0, stream>>>((const ushort_t*)(ws + OFF_XBF),
                                             (const ushort_t*)(ws + OFF_WXT),
                                             (const float*)(ws + OFF_BIAS), ws + OFF_XG, xg32);
    lstm_scan_kernel<<<256, 512, 0, stream>>>((const ushort_t*)(ws + OFF_WHT), ws + OFF_XG,
                                              out, (ushort_t*)(ws + OFF_HBUF),
                                              (uint_t*)(ws + OFF_BAR), xg32);
}